// Round 11
// baseline (208.666 us; speedup 1.0000x reference)
//
#include <hip/hip_runtime.h>
#include <hip/hip_bf16.h>
#include <stdint.h>

typedef unsigned short u16;
typedef unsigned int   u32;

#define S_LEN 2048
#define NQKV  3072
#define NH    32
#define NKV   8
#define SWIN  128
#define NEGV  (-1.0e9f)
#define SCALE_Q 0.35355339059327379f   // 64^-0.25

typedef __attribute__((ext_vector_type(4)))  float  f32x4;
typedef __attribute__((ext_vector_type(16))) float  f32x16;
typedef __attribute__((ext_vector_type(8)))  __bf16 bf16x8;

__device__ __forceinline__ u16 f2bf(float x){
  u32 u = __float_as_uint(x);
  return (u16)((u + 0x7fffu + ((u >> 16) & 1u)) >> 16);   // RNE
}
__device__ __forceinline__ u32 pk2(float a, float b){
  return (u32)f2bf(a) | ((u32)f2bf(b) << 16);
}
__device__ __forceinline__ f32x4 mfma16(bf16x8 a, bf16x8 b, f32x4 c){
  return __builtin_amdgcn_mfma_f32_16x16x32_bf16(a, b, c, 0, 0, 0);
}
__device__ __forceinline__ f32x16 mfma32(bf16x8 a, bf16x8 b, f32x16 c){
  return __builtin_amdgcn_mfma_f32_32x32x16_bf16(a, b, c, 0, 0, 0);
}

typedef __attribute__((address_space(1))) const unsigned int ga_u32;
typedef __attribute__((address_space(3))) unsigned int       ls_u32;
__device__ __forceinline__ void gl16(const void* g, void* l){
  // direct global->LDS, 16B per lane; LDS dest = wave-uniform base + lane*16
  __builtin_amdgcn_global_load_lds((ga_u32*)g, (ls_u32*)l, 16, 0, 0);
}

// ---------------- prep: rope table [S][32][(cos,sin)] + packed bias[3072] ----
__global__ __launch_bounds__(256) void k_prep(const float* __restrict__ bq,
                                              const float* __restrict__ bk,
                                              const float* __restrict__ bv,
                                              float* __restrict__ ropetab,
                                              float* __restrict__ bias3){
  int id = blockIdx.x * 256 + threadIdx.x;        // S*32 threads
  int t = id >> 5, i = id & 31;
  float e = (i * 2.0f) / 64.0f;
  float base = (float)pow(150000.0, (double)e);
  float invf = 1.0f / base;
  float fr = (float)t * invf;
  ropetab[(size_t)id * 2 + 0] = cosf(fr);
  ropetab[(size_t)id * 2 + 1] = sinf(fr);
  if (id < NQKV){
    float b;
    if (id < 2048) b = bq[id];
    else if (id < 2560) b = bk[id - 2048];
    else b = bv[id - 2560];
    bias3[id] = b;
  }
}

// -------- fused packing: A (swizzled) + Wq|Wk|Wv -> Bh + Wo -> Woh ----------
__device__ __forceinline__ void packw_seg(const float* __restrict__ w,
                                          u16* __restrict__ oh,
                                          int N, int NTot, int nOff, int id){
  int p = id / N, n = id % N;     // N literal at call sites -> shifts
  u32 hw[4];
  #pragma unroll
  for (int j = 0; j < 4; ++j){
    float a = w[(size_t)(8 * p + 2 * j) * N + n];
    float b = w[(size_t)(8 * p + 2 * j + 1) * N + n];
    hw[j] = pk2(a, b);
  }
  size_t o = ((size_t)p * NTot + nOff + n) * 8;
  *(uint4*)(oh + o) = make_uint4(hw[0], hw[1], hw[2], hw[3]);
}
__global__ __launch_bounds__(256) void k_packall(const float* __restrict__ hid,
                                                 const float* __restrict__ Wq,
                                                 const float* __restrict__ Wk,
                                                 const float* __restrict__ Wv,
                                                 const float* __restrict__ Wo,
                                                 u16* __restrict__ Ah,
                                                 u16* __restrict__ Bh,
                                                 u16* __restrict__ Woh){
  int b = blockIdx.x;
  if (b < 2048){
    // A: fp32 row-major -> bf16 [M][K/8][8], 8-group swizzle p'=(p&~7)|((p&7)^(r&7))
    int id = b * 256 + threadIdx.x;
    int r = id >> 8, p = id & 255;
    const float4* src = (const float4*)(hid + (size_t)id * 8);
    float4 v0 = src[0], v1 = src[1];
    u32 hw[4];
    hw[0] = pk2(v0.x, v0.y); hw[1] = pk2(v0.z, v0.w);
    hw[2] = pk2(v1.x, v1.y); hw[3] = pk2(v1.z, v1.w);
    int psw = (p & ~7) | ((p & 7) ^ (r & 7));
    size_t o = ((size_t)r * 256 + psw) * 8;
    *(uint4*)(Ah + o) = make_uint4(hw[0], hw[1], hw[2], hw[3]);
  } else if (b < 4096){
    packw_seg(Wq, Bh, 2048, NQKV, 0,    (b - 2048) * 256 + threadIdx.x);
  } else if (b < 4608){
    packw_seg(Wk, Bh, 512,  NQKV, 2048, (b - 4096) * 256 + threadIdx.x);
  } else if (b < 5120){
    packw_seg(Wv, Bh, 512,  NQKV, 2560, (b - 4608) * 256 + threadIdx.x);
  } else {
    packw_seg(Wo, Woh, 2048, 2048, 0,   (b - 5120) * 256 + threadIdx.x);
  }
}

// ------ plain-bf16 GEMM: BK=64, dbuf + global_load_lds + counted vmcnt ------
// ARM=true : A packed [M][K/8][8], 8-group source-swizzled (see k_packall)
// ARM=false: A packed [K/8][M][8] (attn-output layout, conflict-free natively)
// B packed [K/8][N][8]. 128x128 tile, BK=64, 4 waves (2x2), 16x16x32 MFMA.
// EPI=0: C = acc + bias (fp32, row-major)
// EPI=1: fused QKV epilogue -- block-uniform region by n0:
//        cols [0,2048):    rope+scale -> bf16 qoh [h*8+pk][s][8]
//        cols [2048,2560): rope+scale -> bf16 koh [h*8+pk][s][8]
//        cols [2560,3072): bias only  -> bf16 voh [hv][s/8][64][8] (transposed)
// Rope pair (even,odd) dims live in adjacent lanes (col = base+q) -> shfl_xor 1.
template<bool ARM, int EPI>
__global__ __launch_bounds__(256, 2) void k_gemm3(const u16* __restrict__ A,
                                                  const u16* __restrict__ B,
                                                  const float* __restrict__ bias,
                                                  const float* __restrict__ tab,
                                                  u16* __restrict__ qoh,
                                                  u16* __restrict__ koh,
                                                  u16* __restrict__ voh,
                                                  float* __restrict__ C,
                                                  int M, int N, int K){
  __shared__ u16 lds[2][2][1024][8];   // 64 KiB: [buf][A,B][granule][8]
  const int tid = threadIdx.x;
  const int lane = tid & 63, wid = tid >> 6;
  const int q = lane & 15, g = lane >> 4;
  const int m0 = blockIdx.y * 128, n0 = blockIdx.x * 128;
  const int wr = wid >> 1, wc = wid & 1;
  const int pkK = K >> 3;

  f32x4 acc[4][4];
  #pragma unroll
  for (int a = 0; a < 4; ++a)
    #pragma unroll
    for (int b = 0; b < 4; ++b)
      #pragma unroll
      for (int r = 0; r < 4; ++r) acc[a][b][r] = 0.0f;

  size_t aoff[4], boff[4];
  #pragma unroll
  for (int c = 0; c < 4; ++c){
    int L = c * 256 + tid;           // granule index 0..1023
    if (ARM){
      int row = L >> 3, pa = L & 7;
      aoff[c] = ((size_t)(m0 + row) * pkK + pa) * 8;
    } else {
      int pa = L >> 7, row = L & 127;
      aoff[c] = ((size_t)pa * M + m0 + row) * 8;
    }
    int pb = L >> 7, col = L & 127;
    boff[c] = ((size_t)pb * N + n0 + col) * 8;
  }
  const size_t astep = ARM ? (size_t)64 : (size_t)64 * M;   // +8 packets / step
  const size_t bstep = (size_t)64 * N;

  const int NT = K >> 6;   // 32

  auto STAGE = [&](int b){
    #pragma unroll
    for (int c = 0; c < 4; ++c){
      int lbase = c * 256 + wid * 64;   // wave-uniform LDS granule base
      gl16(A + aoff[c], &lds[b][0][lbase][0]);
      gl16(B + boff[c], &lds[b][1][lbase][0]);
      aoff[c] += astep; boff[c] += bstep;
    }
  };

  // prologue: tiles 0,1 in flight; drain only tile 0's 8 loads/thread.
  STAGE(0);
  STAGE(1);
  asm volatile("s_waitcnt vmcnt(8)" ::: "memory");
  __builtin_amdgcn_s_barrier();

  int buf = 0;
  for (int t = 0; t < NT; ++t){
    bf16x8 af[4][2], bf[4][2];
    #pragma unroll
    for (int ms = 0; ms < 4; ++ms){
      int row = wr * 64 + ms * 16 + q;
      #pragma unroll
      for (int kk = 0; kk < 2; ++kk){
        int ia = ARM ? (row * 8 + ((4 * kk + g) ^ (row & 7)))
                     : ((4 * kk + g) * 128 + row);
        af[ms][kk] = *(const bf16x8*)&lds[buf][0][ia][0];
      }
    }
    #pragma unroll
    for (int ns = 0; ns < 4; ++ns){
      int col = wc * 64 + ns * 16 + q;
      #pragma unroll
      for (int kk = 0; kk < 2; ++kk){
        int ib = (4 * kk + g) * 128 + col;
        bf[ns][kk] = *(const bf16x8*)&lds[buf][1][ib][0];
      }
    }
    asm volatile("s_waitcnt lgkmcnt(0)" ::: "memory");
    __builtin_amdgcn_sched_barrier(0);
    __builtin_amdgcn_s_barrier();        // buf free for overwrite (all waves)
    if (t + 2 < NT) STAGE(buf);          // tile t+2 into freed buffer

    #pragma unroll
    for (int kk = 0; kk < 2; ++kk)
      #pragma unroll
      for (int ms = 0; ms < 4; ++ms)
        #pragma unroll
        for (int ns = 0; ns < 4; ++ns)
          acc[ms][ns] = mfma16(af[ms][kk], bf[ns][kk], acc[ms][ns]);

    if (t + 2 < NT){
      asm volatile("s_waitcnt vmcnt(8)" ::: "memory");   // tile t+1 landed
      __builtin_amdgcn_s_barrier();
    } else if (t + 1 < NT){
      asm volatile("s_waitcnt vmcnt(0)" ::: "memory");   // last prefetch drain
      __builtin_amdgcn_s_barrier();
    }
    buf ^= 1;
  }

  if (EPI == 0){
    #pragma unroll
    for (int ns = 0; ns < 4; ++ns){
      int col = n0 + wc * 64 + ns * 16 + q;
      float bb = bias[col];
      #pragma unroll
      for (int ms = 0; ms < 4; ++ms){
        int row = m0 + wr * 64 + ms * 16 + g * 4;
        #pragma unroll
        for (int r = 0; r < 4; ++r)
          C[(size_t)(row + r) * N + col] = acc[ms][ns][r] + bb;
      }
    }
  } else {
    const int ttype = (n0 < 2048) ? 0 : (n0 < 2560 ? 1 : 2);   // block-uniform
    const bool ev = (q & 1) == 0;
    #pragma unroll
    for (int ns = 0; ns < 4; ++ns){
      int col = n0 + wc * 64 + ns * 16 + q;
      float bb = bias[col];
      int j = (col & 63) >> 1;
      #pragma unroll
      for (int ms = 0; ms < 4; ++ms){
        int rbase = m0 + wr * 64 + ms * 16 + g * 4;
        #pragma unroll
        for (int r = 0; r < 4; ++r){
          int row = rbase + r;
          float val = acc[ms][ns][r] + bb;
          if (ttype < 2){
            float pr = __shfl_xor(val, 1);        // partner dim of rope pair
            float e = ev ? val : pr, o = ev ? pr : val;
            float2 cs = *(const float2*)(tab + ((size_t)row * 32 + j) * 2);
            float outv = (ev ? (e * cs.x - o * cs.y)
                             : (o * cs.x + e * cs.y)) * SCALE_Q;
            if (ttype == 0){
              int h = col >> 6, pk = (col & 63) >> 3;
              qoh[(((size_t)(h * 8 + pk)) * S_LEN + row) * 8 + (col & 7)] = f2bf(outv);
            } else {
              int h = (col - 2048) >> 6, pk = (col & 63) >> 3;
              koh[(((size_t)(h * 8 + pk)) * S_LEN + row) * 8 + (col & 7)] = f2bf(outv);
            }
          } else {
            int hv = (col - 2560) >> 6, d = col & 63;
            voh[(((size_t)(hv * 256 + (row >> 3))) * 64 + d) * 8 + (row & 7)] = f2bf(val);
          }
        }
      }
    }
  }
}

// -------- banded attention with sink (flash, swapped QK^T, plain bf16) ------
__global__ __launch_bounds__(256) void k_attn(const u16* __restrict__ qh,
                                              const u16* __restrict__ kh,
                                              const u16* __restrict__ vh,
                                              const float* __restrict__ sinks,
                                              u16* __restrict__ aoh){
  const int lane = threadIdx.x & 63;
  const int wid = threadIdx.x >> 6;
  const int h = blockIdx.x;
  const int hkv = h >> 2;
  const int q0 = blockIdx.y * 128 + wid * 32;
  const int lq = lane & 31;
  const int half = lane >> 5;
  const int qi = q0 + lq;

  bf16x8 qf[4];
  #pragma unroll
  for (int st = 0; st < 4; ++st){
    size_t off = (((size_t)h * 8 + st * 2 + half) * S_LEN + qi) * 8;
    qf[st] = *(const bf16x8*)(qh + off);
  }
  float m = sinks[h];       // sink folded into online softmax: m0=sink, l0=1
  float lsum = 1.0f;
  f32x16 o0, o1;
  #pragma unroll
  for (int r = 0; r < 16; ++r){ o0[r] = 0.0f; o1[r] = 0.0f; }

  const int kb0 = q0 - 128;
  for (int c = 0; c < 9; ++c){
    const int kb = kb0 + c * 32;
    if (kb + 32 <= 0 || kb >= S_LEN) continue;
    const int keyr = kb + lq;
    const int keyc = min(max(keyr, 0), S_LEN - 1);
    f32x16 sc;
    #pragma unroll
    for (int r = 0; r < 16; ++r) sc[r] = 0.0f;
    #pragma unroll
    for (int st = 0; st < 4; ++st){
      size_t ko = (((size_t)hkv * 8 + st * 2 + half) * S_LEN + keyc) * 8;
      bf16x8 kf = *(const bf16x8*)(kh + ko);
      sc = mfma32(kf, qf[st], sc);
    }
    float tmax = -3.0e38f;
    #pragma unroll
    for (int r = 0; r < 16; ++r){
      int key = kb + (r & 3) + 8 * (r >> 2) + 4 * half;
      int dd = qi - key; if (dd < 0) dd = -dd;
      bool ok = (key >= 0) && (key < S_LEN) && (dd <= SWIN);
      sc[r] = ok ? sc[r] : NEGV;
      tmax = fmaxf(tmax, sc[r]);
    }
    tmax = fmaxf(tmax, __shfl_xor(tmax, 32));
    float mn = fmaxf(m, tmax);
    float alpha = __expf(m - mn);
    m = mn;
    float p[16]; float ps = 0.0f;
    #pragma unroll
    for (int r = 0; r < 16; ++r){ p[r] = __expf(sc[r] - mn); ps += p[r]; }
    ps += __shfl_xor(ps, 32);
    lsum = lsum * alpha + ps;
    #pragma unroll
    for (int r = 0; r < 16; ++r){ o0[r] *= alpha; o1[r] *= alpha; }
    u32 wh[8];
    #pragma unroll
    for (int j = 0; j < 8; ++j) wh[j] = pk2(p[2 * j], p[2 * j + 1]);
    bf16x8 pfh[2];
    #pragma unroll
    for (int ks = 0; ks < 2; ++ks){
      u32 x0 = wh[4 * ks + 0], y0 = wh[4 * ks + 2];
      u32 x1 = wh[4 * ks + 1], y1 = wh[4 * ks + 3];
      u32 sx0 = __shfl_xor(x0, 32), sy0 = __shfl_xor(y0, 32);
      u32 sx1 = __shfl_xor(x1, 32), sy1 = __shfl_xor(y1, 32);
      union { u32 u[4]; bf16x8 b; } fb;
      fb.u[0] = half ? sy0 : x0;
      fb.u[1] = half ? sy1 : x1;
      fb.u[2] = half ? y0 : sx0;
      fb.u[3] = half ? y1 : sx1;
      pfh[ks] = fb.b;
    }
    #pragma unroll
    for (int ks = 0; ks < 2; ++ks){
      int kp = kb / 8 + ks * 2 + half;
      kp = min(max(kp, 0), S_LEN / 8 - 1);
      #pragma unroll
      for (int nt = 0; nt < 2; ++nt){
        size_t vo = (((size_t)hkv * 256 + kp) * 64 + nt * 32 + lq) * 8;
        bf16x8 vf = *(const bf16x8*)(vh + vo);
        f32x16 acc = (nt == 0) ? o0 : o1;
        acc = mfma32(vf, pfh[ks], acc);
        if (nt == 0) o0 = acc; else o1 = acc;
      }
    }
  }
  float inv = 1.0f / lsum;
  #pragma unroll
  for (int nt = 0; nt < 2; ++nt){
    f32x16 o = (nt == 0) ? o0 : o1;
    #pragma unroll
    for (int rr = 0; rr < 4; ++rr){
      int d0 = nt * 32 + 8 * rr + 4 * half;
      float v0 = o[rr * 4 + 0] * inv, v1 = o[rr * 4 + 1] * inv;
      float v2 = o[rr * 4 + 2] * inv, v3 = o[rr * 4 + 3] * inv;
      int kp_ = h * 8 + nt * 4 + rr;
      size_t oo = ((size_t)kp_ * S_LEN + qi) * 8 + (d0 & 7);
      uint2 wv; wv.x = pk2(v0, v1); wv.y = pk2(v2, v3);
      *(uint2*)(aoh + oo) = wv;
    }
  }
}

// ---------------------------------------------------------------------------
extern "C" void kernel_launch(void* const* d_in, const int* in_sizes, int n_in,
                              void* d_out, int out_size, void* d_ws, size_t ws_size,
                              hipStream_t stream){
  const float* hid = (const float*)d_in[0];
  const float* Wq  = (const float*)d_in[1];
  const float* bq  = (const float*)d_in[2];
  const float* Wk  = (const float*)d_in[3];
  const float* bk  = (const float*)d_in[4];
  const float* Wv  = (const float*)d_in[5];
  const float* bv  = (const float*)d_in[6];
  const float* Wo  = (const float*)d_in[7];
  const float* bo  = (const float*)d_in[8];
  const float* sinks = (const float*)d_in[9];
  float* out = (float*)d_out;

  char* w = (char*)d_ws;
  size_t off = 0;
  auto alloc = [&](size_t bytes){ void* p = w + off; off += (bytes + 255) & ~(size_t)255; return p; };
  float* ropetab = (float*)alloc((size_t)S_LEN * 32 * 2 * 4);
  float* bias3   = (float*)alloc((size_t)NQKV * 4);
  u16* Ah  = (u16*)alloc((size_t)2048 * 2048 * 2);        // hidden bf16 [M][K/8][8] swz8
  u16* Bh  = (u16*)alloc((size_t)256 * NQKV * 8 * 2);     // Wq|Wk|Wv bf16 [K/8][N][8]
  u16* qph = (u16*)alloc((size_t)NH * 8 * S_LEN * 8 * 2);
  u16* kph = (u16*)alloc((size_t)NKV * 8 * S_LEN * 8 * 2);
  u16* vph = (u16*)alloc((size_t)NKV * 256 * 64 * 8 * 2);
  u16* aoh = (u16*)alloc((size_t)256 * S_LEN * 8 * 2);    // attn out bf16 [K/8][S][8]
  u16* Woh = (u16*)alloc((size_t)256 * 2048 * 8 * 2);     // Wo bf16 [K/8][N][8]
  (void)in_sizes; (void)n_in; (void)out_size; (void)ws_size;

  k_prep<<<256, 256, 0, stream>>>(bq, bk, bv, ropetab, bias3);
  k_packall<<<7168, 256, 0, stream>>>(hid, Wq, Wk, Wv, Wo, Ah, Bh, Woh);
  k_gemm3<true, 1><<<dim3(NQKV / 128, 2048 / 128), 256, 0, stream>>>(
      Ah, Bh, bias3, ropetab, qph, kph, vph, nullptr, 2048, NQKV, 2048);
  k_attn<<<dim3(NH, S_LEN / 128), 256, 0, stream>>>(qph, kph, vph, sinks, aoh);
  k_gemm3<false, 0><<<dim3(2048 / 128, 2048 / 128), 256, 0, stream>>>(
      aoh, Woh, bo, nullptr, nullptr, nullptr, nullptr, out, 2048, 2048, 2048);
}

// Round 13
// 202.092 us; speedup vs baseline: 1.0325x; 1.0325x over previous
//
#include <hip/hip_runtime.h>
#include <hip/hip_bf16.h>
#include <stdint.h>

typedef unsigned short u16;
typedef unsigned int   u32;

#define S_LEN 2048
#define NQKV  3072
#define NH    32
#define NKV   8
#define SWIN  128
#define NEGV  (-1.0e9f)
#define SCALE_Q 0.35355339059327379f   // 64^-0.25

typedef __attribute__((ext_vector_type(4)))  float  f32x4;
typedef __attribute__((ext_vector_type(16))) float  f32x16;
typedef __attribute__((ext_vector_type(8)))  __bf16 bf16x8;

__device__ __forceinline__ u16 f2bf(float x){
  u32 u = __float_as_uint(x);
  return (u16)((u + 0x7fffu + ((u >> 16) & 1u)) >> 16);   // RNE
}
__device__ __forceinline__ u32 pk2(float a, float b){
  return (u32)f2bf(a) | ((u32)f2bf(b) << 16);
}
__device__ __forceinline__ f32x4 mfma16(bf16x8 a, bf16x8 b, f32x4 c){
  return __builtin_amdgcn_mfma_f32_16x16x32_bf16(a, b, c, 0, 0, 0);
}
__device__ __forceinline__ f32x16 mfma32(bf16x8 a, bf16x8 b, f32x16 c){
  return __builtin_amdgcn_mfma_f32_32x32x16_bf16(a, b, c, 0, 0, 0);
}

typedef __attribute__((address_space(1))) const unsigned int ga_u32;
typedef __attribute__((address_space(3))) unsigned int       ls_u32;
__device__ __forceinline__ void gl16(const void* g, void* l){
  // direct global->LDS, 16B per lane; LDS dest = wave-uniform base + lane*16
  __builtin_amdgcn_global_load_lds((ga_u32*)g, (ls_u32*)l, 16, 0, 0);
}

// ---- fused packing + prep: A(swz) | Wq|Wk|Wv -> Bh | Wo -> Woh | ropetab ----
__device__ __forceinline__ void packw_seg(const float* __restrict__ w,
                                          u16* __restrict__ oh,
                                          int N, int NTot, int nOff, int id){
  int p = id / N, n = id % N;     // N literal at call sites -> shifts
  u32 hw[4];
  #pragma unroll
  for (int j = 0; j < 4; ++j){
    float a = w[(size_t)(8 * p + 2 * j) * N + n];
    float b = w[(size_t)(8 * p + 2 * j + 1) * N + n];
    hw[j] = pk2(a, b);
  }
  size_t o = ((size_t)p * NTot + nOff + n) * 8;
  *(uint4*)(oh + o) = make_uint4(hw[0], hw[1], hw[2], hw[3]);
}
__global__ __launch_bounds__(256) void k_packall(const float* __restrict__ hid,
                                                 const float* __restrict__ Wq,
                                                 const float* __restrict__ Wk,
                                                 const float* __restrict__ Wv,
                                                 const float* __restrict__ Wo,
                                                 const float* __restrict__ bq,
                                                 const float* __restrict__ bk,
                                                 const float* __restrict__ bv,
                                                 u16* __restrict__ Ah,
                                                 u16* __restrict__ Bh,
                                                 u16* __restrict__ Woh,
                                                 float* __restrict__ ropetab,
                                                 float* __restrict__ bias3){
  int b = blockIdx.x;
  if (b < 2048){
    // A: fp32 row-major -> bf16 [M][K/8][8], 8-group swizzle p'=(p&~7)|((p&7)^(r&7))
    int id = b * 256 + threadIdx.x;
    int r = id >> 8, p = id & 255;
    const float4* src = (const float4*)(hid + (size_t)id * 8);
    float4 v0 = src[0], v1 = src[1];
    u32 hw[4];
    hw[0] = pk2(v0.x, v0.y); hw[1] = pk2(v0.z, v0.w);
    hw[2] = pk2(v1.x, v1.y); hw[3] = pk2(v1.z, v1.w);
    int psw = (p & ~7) | ((p & 7) ^ (r & 7));
    size_t o = ((size_t)r * 256 + psw) * 8;
    *(uint4*)(Ah + o) = make_uint4(hw[0], hw[1], hw[2], hw[3]);
  } else if (b < 4096){
    packw_seg(Wq, Bh, 2048, NQKV, 0,    (b - 2048) * 256 + threadIdx.x);
  } else if (b < 4608){
    packw_seg(Wk, Bh, 512,  NQKV, 2048, (b - 4096) * 256 + threadIdx.x);
  } else if (b < 5120){
    packw_seg(Wv, Bh, 512,  NQKV, 2560, (b - 4608) * 256 + threadIdx.x);
  } else if (b < 7168){
    packw_seg(Wo, Woh, 2048, 2048, 0,   (b - 5120) * 256 + threadIdx.x);
  } else {
    // prep: rope table [S][32][(cos,sin)] + packed bias[3072]
    int id = (b - 7168) * 256 + threadIdx.x;    // S*32 threads
    int t = id >> 5, i = id & 31;
    float e = (i * 2.0f) / 64.0f;
    float base = (float)pow(150000.0, (double)e);
    float invf = 1.0f / base;
    float fr = (float)t * invf;
    ropetab[(size_t)id * 2 + 0] = cosf(fr);
    ropetab[(size_t)id * 2 + 1] = sinf(fr);
    if (id < NQKV){
      float bb;
      if (id < 2048) bb = bq[id];
      else if (id < 2560) bb = bk[id - 2048];
      else bb = bv[id - 2560];
      bias3[id] = bb;
    }
  }
}

// ------ plain-bf16 GEMM: BK=64, dbuf + global_load_lds + counted vmcnt ------
// ARM=true : A packed [M][K/8][8], 8-group source-swizzled (see k_packall)
// ARM=false: A packed [K/8][M][8] (attn-output layout, conflict-free natively)
// B packed [K/8][N][8]. 128x128 tile, BK=64, 4 waves (2x2), 16x16x32 MFMA.
// EPI=0: C = acc + bias (fp32, row-major)
// EPI=1: fused QKV epilogue, LDS-staged for coalesced bf16 stores:
//        cols [0,2048):    rope+scale -> qoh [h*8+pk][s][8]
//        cols [2048,2560): rope+scale -> koh [h*8+pk][s][8]
//        cols [2560,3072): bias only  -> voh [hv][s/8][64][8] (transposed)
// LDS reuse is safe: final mid-loop lgkmcnt(0)+barrier ends all LDS reads,
// and the last gl16 batch was drained with vmcnt(0) at t=NT-2.
template<bool ARM, int EPI>
__global__ __launch_bounds__(256, 2) void k_gemm3(const u16* __restrict__ A,
                                                  const u16* __restrict__ B,
                                                  const float* __restrict__ bias,
                                                  const float* __restrict__ tab,
                                                  u16* __restrict__ qoh,
                                                  u16* __restrict__ koh,
                                                  u16* __restrict__ voh,
                                                  float* __restrict__ C,
                                                  int M, int N, int K){
  __shared__ u16 lds[2][2][1024][8];   // 64 KiB: [buf][A,B][granule][8]
  const int tid = threadIdx.x;
  const int lane = tid & 63, wid = tid >> 6;
  const int q = lane & 15, g = lane >> 4;
  const int m0 = blockIdx.y * 128, n0 = blockIdx.x * 128;
  const int wr = wid >> 1, wc = wid & 1;
  const int pkK = K >> 3;

  f32x4 acc[4][4];
  #pragma unroll
  for (int a = 0; a < 4; ++a)
    #pragma unroll
    for (int b = 0; b < 4; ++b)
      #pragma unroll
      for (int r = 0; r < 4; ++r) acc[a][b][r] = 0.0f;

  size_t aoff[4], boff[4];
  #pragma unroll
  for (int c = 0; c < 4; ++c){
    int L = c * 256 + tid;           // granule index 0..1023
    if (ARM){
      int row = L >> 3, pa = L & 7;
      aoff[c] = ((size_t)(m0 + row) * pkK + pa) * 8;
    } else {
      int pa = L >> 7, row = L & 127;
      aoff[c] = ((size_t)pa * M + m0 + row) * 8;
    }
    int pb = L >> 7, col = L & 127;
    boff[c] = ((size_t)pb * N + n0 + col) * 8;
  }
  const size_t astep = ARM ? (size_t)64 : (size_t)64 * M;   // +8 packets / step
  const size_t bstep = (size_t)64 * N;

  const int NT = K >> 6;   // 32

  auto STAGE = [&](int b){
    #pragma unroll
    for (int c = 0; c < 4; ++c){
      int lbase = c * 256 + wid * 64;   // wave-uniform LDS granule base
      gl16(A + aoff[c], &lds[b][0][lbase][0]);
      gl16(B + boff[c], &lds[b][1][lbase][0]);
      aoff[c] += astep; boff[c] += bstep;
    }
  };

  // prologue: tiles 0,1 in flight; drain only tile 0's 8 loads/thread.
  STAGE(0);
  STAGE(1);
  asm volatile("s_waitcnt vmcnt(8)" ::: "memory");
  __builtin_amdgcn_s_barrier();

  int buf = 0;
  for (int t = 0; t < NT; ++t){
    bf16x8 af[4][2], bf[4][2];
    #pragma unroll
    for (int ms = 0; ms < 4; ++ms){
      int row = wr * 64 + ms * 16 + q;
      #pragma unroll
      for (int kk = 0; kk < 2; ++kk){
        int ia = ARM ? (row * 8 + ((4 * kk + g) ^ (row & 7)))
                     : ((4 * kk + g) * 128 + row);
        af[ms][kk] = *(const bf16x8*)&lds[buf][0][ia][0];
      }
    }
    #pragma unroll
    for (int ns = 0; ns < 4; ++ns){
      int col = wc * 64 + ns * 16 + q;
      #pragma unroll
      for (int kk = 0; kk < 2; ++kk){
        int ib = (4 * kk + g) * 128 + col;
        bf[ns][kk] = *(const bf16x8*)&lds[buf][1][ib][0];
      }
    }
    asm volatile("s_waitcnt lgkmcnt(0)" ::: "memory");
    __builtin_amdgcn_sched_barrier(0);
    __builtin_amdgcn_s_barrier();        // buf free for overwrite (all waves)
    if (t + 2 < NT) STAGE(buf);          // tile t+2 into freed buffer

    #pragma unroll
    for (int kk = 0; kk < 2; ++kk)
      #pragma unroll
      for (int ms = 0; ms < 4; ++ms)
        #pragma unroll
        for (int ns = 0; ns < 4; ++ns)
          acc[ms][ns] = mfma16(af[ms][kk], bf[ns][kk], acc[ms][ns]);

    if (t + 2 < NT){
      asm volatile("s_waitcnt vmcnt(8)" ::: "memory");   // tile t+1 landed
      __builtin_amdgcn_s_barrier();
    } else if (t + 1 < NT){
      asm volatile("s_waitcnt vmcnt(0)" ::: "memory");   // last prefetch drain
      __builtin_amdgcn_s_barrier();
    }
    buf ^= 1;
  }

  if (EPI == 0){
    #pragma unroll
    for (int ns = 0; ns < 4; ++ns){
      int col = n0 + wc * 64 + ns * 16 + q;
      float bb = bias[col];
      #pragma unroll
      for (int ms = 0; ms < 4; ++ms){
        int row = m0 + wr * 64 + ms * 16 + g * 4;
        #pragma unroll
        for (int r = 0; r < 4; ++r)
          C[(size_t)(row + r) * N + col] = acc[ms][ns][r] + bb;
      }
    }
  } else {
    // ---- LDS-staged epilogue: scratch in OUTPUT-chunk order, then 8
    // coalesced uint4 stores per wave (64 lanes x 16B = 1KB/instr).
    const int ttype = (n0 < 2048) ? 0 : (n0 < 2560 ? 1 : 2);   // block-uniform
    const bool ev = (q & 1) == 0;
    const int colbase = n0 + wc * 64;                // one head per quadrant
    u16* sc = ((u16*)lds) + wid * 4096;              // 8KB scratch per wave
    #pragma unroll
    for (int ns = 0; ns < 4; ++ns){
      int col = colbase + ns * 16 + q;
      float bb = bias[col];
      int j = (col & 63) >> 1;
      #pragma unroll
      for (int ms = 0; ms < 4; ++ms){
        #pragma unroll
        for (int r = 0; r < 4; ++r){
          int lrow = ms * 16 + g * 4 + r;
          int row = m0 + wr * 64 + lrow;
          float val = acc[ms][ns][r] + bb;
          if (ttype < 2){
            float pr = __shfl_xor(val, 1);           // partner dim of rope pair
            float e = ev ? val : pr, o = ev ? pr : val;
            float2 cs = *(const float2*)(tab + ((size_t)row * 32 + j) * 2);
            float outv = (ev ? (e * cs.x - o * cs.y)
                             : (o * cs.x + e * cs.y)) * SCALE_Q;
            // chunk order (pk, lrow, col&7)
            sc[((col & 63) >> 3) * 512 + lrow * 8 + (col & 7)] = f2bf(outv);
          } else {
            // chunk order (rowgrp, d, lrow&7)
            sc[(lrow >> 3) * 512 + (col & 63) * 8 + (lrow & 7)] = f2bf(val);
          }
        }
      }
    }
    asm volatile("s_waitcnt lgkmcnt(0)" ::: "memory");
    __builtin_amdgcn_sched_barrier(0);               // wave-local: no barrier needed
    if (ttype < 2){
      u16* base = (ttype == 0) ? qoh : koh;
      int h = (ttype == 0) ? (colbase >> 6) : ((colbase - 2048) >> 6);
      int row_g = m0 + wr * 64 + lane;
      #pragma unroll
      for (int i = 0; i < 8; ++i){
        uint4 vchunk = *(const uint4*)&sc[(i * 64 + lane) * 8];
        *(uint4*)&base[(((size_t)(h * 8 + i)) * S_LEN + row_g) * 8] = vchunk;
      }
    } else {
      int hv = (colbase - 2560) >> 6;
      int rg0 = (m0 + wr * 64) >> 3;
      #pragma unroll
      for (int i = 0; i < 8; ++i){
        uint4 vchunk = *(const uint4*)&sc[(i * 64 + lane) * 8];
        *(uint4*)&voh[(((size_t)(hv * 256 + rg0 + i)) * 64 + lane) * 8] = vchunk;
      }
    }
  }
}

// -------- banded attention with sink (flash, swapped QK^T, plain bf16) ------
__global__ __launch_bounds__(256) void k_attn(const u16* __restrict__ qh,
                                              const u16* __restrict__ kh,
                                              const u16* __restrict__ vh,
                                              const float* __restrict__ sinks,
                                              u16* __restrict__ aoh){
  const int lane = threadIdx.x & 63;
  const int wid = threadIdx.x >> 6;
  const int h = blockIdx.x;
  const int hkv = h >> 2;
  const int q0 = blockIdx.y * 128 + wid * 32;
  const int lq = lane & 31;
  const int half = lane >> 5;
  const int qi = q0 + lq;

  bf16x8 qf[4];
  #pragma unroll
  for (int st = 0; st < 4; ++st){
    size_t off = (((size_t)h * 8 + st * 2 + half) * S_LEN + qi) * 8;
    qf[st] = *(const bf16x8*)(qh + off);
  }
  float m = sinks[h];       // sink folded into online softmax: m0=sink, l0=1
  float lsum = 1.0f;
  f32x16 o0, o1;
  #pragma unroll
  for (int r = 0; r < 16; ++r){ o0[r] = 0.0f; o1[r] = 0.0f; }

  const int kb0 = q0 - 128;
  for (int c = 0; c < 9; ++c){
    const int kb = kb0 + c * 32;
    if (kb + 32 <= 0 || kb >= S_LEN) continue;
    const int keyr = kb + lq;
    const int keyc = min(max(keyr, 0), S_LEN - 1);
    f32x16 sc;
    #pragma unroll
    for (int r = 0; r < 16; ++r) sc[r] = 0.0f;
    #pragma unroll
    for (int st = 0; st < 4; ++st){
      size_t ko = (((size_t)hkv * 8 + st * 2 + half) * S_LEN + keyc) * 8;
      bf16x8 kf = *(const bf16x8*)(kh + ko);
      sc = mfma32(kf, qf[st], sc);
    }
    float tmax = -3.0e38f;
    #pragma unroll
    for (int r = 0; r < 16; ++r){
      int key = kb + (r & 3) + 8 * (r >> 2) + 4 * half;
      int dd = qi - key; if (dd < 0) dd = -dd;
      bool ok = (key >= 0) && (key < S_LEN) && (dd <= SWIN);
      sc[r] = ok ? sc[r] : NEGV;
      tmax = fmaxf(tmax, sc[r]);
    }
    tmax = fmaxf(tmax, __shfl_xor(tmax, 32));
    float mn = fmaxf(m, tmax);
    float alpha = __expf(m - mn);
    m = mn;
    float p[16]; float ps = 0.0f;
    #pragma unroll
    for (int r = 0; r < 16; ++r){ p[r] = __expf(sc[r] - mn); ps += p[r]; }
    ps += __shfl_xor(ps, 32);
    lsum = lsum * alpha + ps;
    #pragma unroll
    for (int r = 0; r < 16; ++r){ o0[r] *= alpha; o1[r] *= alpha; }
    u32 wh[8];
    #pragma unroll
    for (int j = 0; j < 8; ++j) wh[j] = pk2(p[2 * j], p[2 * j + 1]);
    bf16x8 pfh[2];
    #pragma unroll
    for (int ks = 0; ks < 2; ++ks){
      u32 x0 = wh[4 * ks + 0], y0 = wh[4 * ks + 2];
      u32 x1 = wh[4 * ks + 1], y1 = wh[4 * ks + 3];
      u32 sx0 = __shfl_xor(x0, 32), sy0 = __shfl_xor(y0, 32);
      u32 sx1 = __shfl_xor(x1, 32), sy1 = __shfl_xor(y1, 32);
      union { u32 u[4]; bf16x8 b; } fb;
      fb.u[0] = half ? sy0 : x0;
      fb.u[1] = half ? sy1 : x1;
      fb.u[2] = half ? y0 : sx0;
      fb.u[3] = half ? y1 : sx1;
      pfh[ks] = fb.b;
    }
    #pragma unroll
    for (int ks = 0; ks < 2; ++ks){
      int kp = kb / 8 + ks * 2 + half;
      kp = min(max(kp, 0), S_LEN / 8 - 1);
      #pragma unroll
      for (int nt = 0; nt < 2; ++nt){
        size_t vo = (((size_t)hkv * 256 + kp) * 64 + nt * 32 + lq) * 8;
        bf16x8 vf = *(const bf16x8*)(vh + vo);
        f32x16 acc = (nt == 0) ? o0 : o1;
        acc = mfma32(vf, pfh[ks], acc);
        if (nt == 0) o0 = acc; else o1 = acc;
      }
    }
  }
  float inv = 1.0f / lsum;
  #pragma unroll
  for (int nt = 0; nt < 2; ++nt){
    f32x16 o = (nt == 0) ? o0 : o1;
    #pragma unroll
    for (int rr = 0; rr < 4; ++rr){
      int d0 = nt * 32 + 8 * rr + 4 * half;
      float v0 = o[rr * 4 + 0] * inv, v1 = o[rr * 4 + 1] * inv;
      float v2 = o[rr * 4 + 2] * inv, v3 = o[rr * 4 + 3] * inv;
      int kp_ = h * 8 + nt * 4 + rr;
      size_t oo = ((size_t)kp_ * S_LEN + qi) * 8 + (d0 & 7);
      uint2 wv; wv.x = pk2(v0, v1); wv.y = pk2(v2, v3);
      *(uint2*)(aoh + oo) = wv;
    }
  }
}

// ---------------------------------------------------------------------------
extern "C" void kernel_launch(void* const* d_in, const int* in_sizes, int n_in,
                              void* d_out, int out_size, void* d_ws, size_t ws_size,
                              hipStream_t stream){
  const float* hid = (const float*)d_in[0];
  const float* Wq  = (const float*)d_in[1];
  const float* bq  = (const float*)d_in[2];
  const float* Wk  = (const float*)d_in[3];
  const float* bk  = (const float*)d_in[4];
  const float* Wv  = (const float*)d_in[5];
  const float* bv  = (const float*)d_in[6];
  const float* Wo  = (const float*)d_in[7];
  const float* bo  = (const float*)d_in[8];
  const float* sinks = (const float*)d_in[9];
  float* out = (float*)d_out;

  char* w = (char*)d_ws;
  size_t off = 0;
  auto alloc = [&](size_t bytes){ void* p = w + off; off += (bytes + 255) & ~(size_t)255; return p; };
  float* ropetab = (float*)alloc((size_t)S_LEN * 32 * 2 * 4);
  float* bias3   = (float*)alloc((size_t)NQKV * 4);
  u16* Ah  = (u16*)alloc((size_t)2048 * 2048 * 2);        // hidden bf16 [M][K/8][8] swz8
  u16* Bh  = (u16*)alloc((size_t)256 * NQKV * 8 * 2);     // Wq|Wk|Wv bf16 [K/8][N][8]
  u16* qph = (u16*)alloc((size_t)NH * 8 * S_LEN * 8 * 2);
  u16* kph = (u16*)alloc((size_t)NKV * 8 * S_LEN * 8 * 2);
  u16* vph = (u16*)alloc((size_t)NKV * 256 * 64 * 8 * 2);
  u16* aoh = (u16*)alloc((size_t)256 * S_LEN * 8 * 2);    // attn out bf16 [K/8][S][8]
  u16* Woh = (u16*)alloc((size_t)256 * 2048 * 8 * 2);     // Wo bf16 [K/8][N][8]
  (void)in_sizes; (void)n_in; (void)out_size; (void)ws_size;

  k_packall<<<7424, 256, 0, stream>>>(hid, Wq, Wk, Wv, Wo, bq, bk, bv,
                                      Ah, Bh, Woh, ropetab, bias3);
  k_gemm3<true, 1><<<dim3(NQKV / 128, 2048 / 128), 256, 0, stream>>>(
      Ah, Bh, bias3, ropetab, qph, kph, vph, nullptr, 2048, NQKV, 2048);
  k_attn<<<dim3(NH, S_LEN / 128), 256, 0, stream>>>(qph, kph, vph, sinks, aoh);
  k_gemm3<false, 0><<<dim3(2048 / 128, 2048 / 128), 256, 0, stream>>>(
      aoh, Woh, bo, nullptr, nullptr, nullptr, nullptr, out, 2048, 2048, 2048);
}